// Round 10
// baseline (681.943 us; speedup 1.0000x reference)
//
#include <hip/hip_runtime.h>
#include <hip/hip_bf16.h>
#include <math.h>

#define NB 2
#define NS 2048
#define ND 2048
#define NH 16
#define DNOPE 128
#define DROPE 64
#define DVAL 128
#define RANK 512
#define QW (NH*(DNOPE+DROPE))    // 3072
#define AW (RANK+DROPE)          // 576
#define AWPAD 640
#define BW (NH*(DNOPE+DVAL))     // 4096
#define OW (NH*DVAL)             // 2048
#define ATT_SCALE 0.07216878364870322f

typedef __attribute__((ext_vector_type(8))) short short8;
typedef __attribute__((ext_vector_type(4))) float f32x4;

__device__ __forceinline__ float b2f(unsigned short u) {
  unsigned x = ((unsigned)u) << 16; float f; __builtin_memcpy(&f, &x, 4); return f;
}
__device__ __forceinline__ unsigned short f2b(float f) {
  unsigned x; __builtin_memcpy(&x, &f, 4);
  unsigned r = (x + 0x7fffu + ((x >> 16) & 1u)) >> 16;
  return (unsigned short)r;
}
__device__ __forceinline__ void gload16(const void* g, void* lds) {
  __builtin_amdgcn_global_load_lds((const __attribute__((address_space(1))) void*)g,
                                   (__attribute__((address_space(3))) void*)lds, 16, 0, 0);
}

// ---------- fp32 -> bf16 flat convert ----------
__global__ __launch_bounds__(256) void k_cvt(const float* __restrict__ X,
                                             unsigned short* __restrict__ Y) {
  long i = ((long)blockIdx.x * 256 + threadIdx.x) * 4;
  float4 v = *(const float4*)(X + i);
  ushort4 o;
  o.x = f2b(v.x); o.y = f2b(v.y); o.z = f2b(v.z); o.w = f2b(v.w);
  *(ushort4*)(Y + i) = o;
}

// ---------- transpose+convert: W fp32 [K][N] -> WT bf16 [Npad][K], zero pad ----------
__global__ __launch_bounds__(256) void k_transpose(const float* __restrict__ W,
                                                   unsigned short* __restrict__ WT,
                                                   int K, int N) {
  __shared__ float t[32][33];
  const int k0 = blockIdx.x * 32, n0 = blockIdx.y * 32;
  const int tx = threadIdx.x & 31, ty = threadIdx.x >> 5;
  #pragma unroll
  for (int i = 0; i < 32; i += 8) {
    int n = n0 + tx;
    float v = (n < N) ? W[(size_t)(k0 + ty + i) * N + n] : 0.f;
    t[ty + i][tx] = v;
  }
  __syncthreads();
  #pragma unroll
  for (int i = 0; i < 32; i += 8)
    WT[(size_t)(n0 + ty + i) * K + k0 + tx] = f2b(t[tx][ty + i]);
}

// ---------- bf16 MFMA GEMM (validated round 6) + optional transposed-V epilogue ----------
// VTOUT: when col-tile sits in the V half of a head block (bn&128), write
// vT[(h*128+d)][t] instead of C (row-major K-nope half written normally).
template <typename OutT, bool VTOUT>
__global__ __launch_bounds__(256) void gemm_bf16(
    const unsigned short* __restrict__ A, const unsigned short* __restrict__ BT,
    OutT* __restrict__ C, unsigned short* __restrict__ vT,
    int M, int N, int K, int lda) {
  __shared__ short8 AsV[1024];
  __shared__ short8 BsV[1024];
  const int tid = threadIdx.x;
  const int l = tid & 63, w = tid >> 6;
  // XCD-aware block swizzle (grid always divisible by 8 here)
  const int nwg = gridDim.x * gridDim.y;
  const int bid = blockIdx.y * gridDim.x + blockIdx.x;
  const int sbid = (bid & 7) * (nwg >> 3) + (bid >> 3);
  const int bx = sbid % gridDim.x, by = sbid / gridDim.x;
  const int bm = by * 128, bn = bx * 128;
  const int wm = (w >> 1) * 64, wn = (w & 1) * 64;
  f32x4 acc[4][4] = {};

  const int srow = tid >> 3;
  const int gk   = ((((tid & 7) * 16) ^ ((srow & 7) << 4)) >> 1);
  const int sw   = l & 7;

  for (int k0 = 0; k0 < K; k0 += 64) {
    #pragma unroll
    for (int i = 0; i < 4; ++i) {
      const int row = i * 32 + srow;
      gload16(A + (size_t)(bm + row) * lda + k0 + gk, (char*)AsV + i * 4096 + w * 1024);
      gload16(BT + (size_t)(bn + row) * K   + k0 + gk, (char*)BsV + i * 4096 + w * 1024);
    }
    __syncthreads();
    #pragma unroll
    for (int kk2 = 0; kk2 < 2; ++kk2) {
      const int kb = kk2 * 4 + (l >> 4);
      short8 af[4], bg[4];
      #pragma unroll
      for (int mi = 0; mi < 4; ++mi)
        af[mi] = AsV[(wm + mi * 16 + (l & 15)) * 8 + (kb ^ sw)];
      #pragma unroll
      for (int ni = 0; ni < 4; ++ni)
        bg[ni] = BsV[(wn + ni * 16 + (l & 15)) * 8 + (kb ^ sw)];
      #pragma unroll
      for (int mi = 0; mi < 4; ++mi)
        #pragma unroll
        for (int ni = 0; ni < 4; ++ni)
          acc[mi][ni] = __builtin_amdgcn_mfma_f32_16x16x32_bf16(af[mi], bg[ni], acc[mi][ni], 0, 0, 0);
    }
    __syncthreads();
  }

  const int r0 = bm + wm + (l >> 4) * 4;
  const int c0 = bn + wn + (l & 15);
  if (VTOUT && (bn & 128)) {
    // V half: col = c0+ni*16 -> h = col>>8, d = col&127; write vT[(h*128+d)][t0..t0+3]
    #pragma unroll
    for (int mi = 0; mi < 4; ++mi)
      #pragma unroll
      for (int ni = 0; ni < 4; ++ni) {
        const int col = c0 + ni * 16;
        const int hh = col >> 8, dd = col & 127;
        ushort4 u;
        u.x = f2b(acc[mi][ni][0]); u.y = f2b(acc[mi][ni][1]);
        u.z = f2b(acc[mi][ni][2]); u.w = f2b(acc[mi][ni][3]);
        *(ushort4*)&vT[(size_t)(hh * 128 + dd) * NS + (r0 + mi * 16)] = u;
      }
  } else {
    #pragma unroll
    for (int mi = 0; mi < 4; ++mi)
      #pragma unroll
      for (int ni = 0; ni < 4; ++ni) {
        const int col = c0 + ni * 16;
        if (col < N) {
          #pragma unroll
          for (int j = 0; j < 4; ++j) {
            float v = acc[mi][ni][j];
            if constexpr (__is_same(OutT, float))
              C[(size_t)(r0 + mi * 16 + j) * N + col] = v;
            else
              C[(size_t)(r0 + mi * 16 + j) * N + col] = f2b(v);
          }
        }
      }
  }
}

// ---------- RMSNorm on bf16 kva rows ----------
__global__ __launch_bounds__(256) void k_rms_b(unsigned short* __restrict__ kva,
                                               const float* __restrict__ w) {
  const int row = blockIdx.x;
  unsigned short* p = kva + (long)row * AW;
  __shared__ float sd[256];
  float ss = 0.f;
  for (int j = threadIdx.x; j < RANK; j += 256) { float v = b2f(p[j]); ss += v * v; }
  sd[threadIdx.x] = ss;
  __syncthreads();
  for (int st = 128; st > 0; st >>= 1) {
    if (threadIdx.x < st) sd[threadIdx.x] += sd[threadIdx.x + st];
    __syncthreads();
  }
  const float sc = rsqrtf(sd[0] / (float)RANK + 1e-6f);
  for (int j = threadIdx.x; j < RANK; j += 256) p[j] = f2b(b2f(p[j]) * sc * w[j]);
}

// ---------- RoPE k_pe ----------
__global__ __launch_bounds__(64) void k_ropek_b(unsigned short* __restrict__ kva) {
  const int row = blockIdx.x;
  const int i = threadIdx.x;
  if (i >= 32) return;
  const double invf = pow(10000.0, -(double)i / 32.0);
  const double ang = (double)row * invf;
  const float c = (float)cos(ang), s = (float)sin(ang);
  unsigned short* p = kva + (long)row * AW + RANK + 2 * i;
  const float x0 = b2f(p[0]), x1 = b2f(p[1]);
  p[0] = f2b(x0 * c - x1 * s);
  p[1] = f2b(x0 * s + x1 * c);
}

// ---------- RoPE q_pe ----------
__global__ __launch_bounds__(512) void k_ropeq_b(unsigned short* __restrict__ q) {
  const int row = blockIdx.x;
  const int h = threadIdx.x >> 5;
  const int i = threadIdx.x & 31;
  const double invf = pow(10000.0, -(double)i / 32.0);
  const double ang = (double)row * invf;
  const float c = (float)cos(ang), s = (float)sin(ang);
  unsigned short* p = q + (long)row * QW + h * (DNOPE + DROPE) + DNOPE + 2 * i;
  const float x0 = b2f(p[0]), x1 = b2f(p[1]);
  p[0] = f2b(x0 * c - x1 * s);
  p[1] = f2b(x0 * s + x1 * c);
}

// ---------- MFMA flash attention (V^T pre-transposed in global; defer-max) ----------
// grid (32, 16), 256 thr = 4 waves, wave owns 16 q-rows, K tiles of 64 keys.
#define QBLK 64
#define KBLK 64
#define KSL 24               // 16B slots per K row (192 bf16)
#define PLS 72               // P row stride (elems)
__global__ __launch_bounds__(256) void k_attn_mfma(
    const unsigned short* __restrict__ q,
    const unsigned short* __restrict__ kvb,
    const unsigned short* __restrict__ kva,
    const unsigned short* __restrict__ vT,
    unsigned short* __restrict__ att) {
  __shared__ short8 Ks[KBLK * KSL];                       // 24 KB, slot-swizzled
  __shared__ short8 Vs[DVAL * 8];                         // 16 KB: [d][8 slots], slot-swizzled
  __shared__ __align__(16) unsigned short Pl[QBLK * PLS]; // 9 KB
  const int tid = threadIdx.x;
  const int l = tid & 63, w = tid >> 6;
  const int g = l >> 4, r16 = l & 15;
  const int h = blockIdx.y;
  // causal pairing: blocks (bx,h) and (bx,h+8) are 256 apart -> same CU; work sums to 33 tiles
  const int qt = (h < 8) ? blockIdx.x : (NS / QBLK - 1) - blockIdx.x;
  const int qrow0 = qt * QBLK + w * 16;

  // Q A-frags: 16 rows x 192, resident in registers
  short8 aq[6];
  {
    const unsigned short* qp = q + (size_t)(qrow0 + r16) * QW + h * 192 + g * 8;
    #pragma unroll
    for (int f = 0; f < 6; ++f) aq[f] = *(const short8*)(qp + f * 32);
  }

  f32x4 o[8] = {};
  float m_j[4], l_j[4];
  #pragma unroll
  for (int j = 0; j < 4; ++j) { m_j[j] = -1e30f; l_j[j] = 0.f; }

  for (int kt = 0; kt <= qt; ++kt) {
    const int kbase = kt * KBLK;
    // stage K (64x192) swizzled: phys slot p holds logical s = (p&~7)|((p&7)^(row&7))
    #pragma unroll
    for (int i = 0; i < 6; ++i) {
      const int chunk = i * 256 + tid;
      const int row = chunk / KSL, p = chunk % KSL;
      const int s = (p & ~7) | ((p & 7) ^ (row & 7));
      const int d0 = s * 8;
      const unsigned short* src =
          (d0 < DNOPE) ? kvb + (size_t)(kbase + row) * BW + h * 256 + d0
                       : kva + (size_t)(kbase + row) * AW + RANK + (d0 - DNOPE);
      gload16(src, (char*)Ks + (size_t)(i * 256 + (tid & ~63)) * 16);
    }
    // stage V^T from global vT (linear LDS dest, inverse-swizzled global source):
    // Vs[row][p] <- vT[h*128+row][kbase + (p^(row&7))*8 .. +7]
    #pragma unroll
    for (int i = 0; i < 4; ++i) {
      const int row = (i * 4 + w) * 8 + (l >> 3);
      const int p = l & 7;
      gload16(vT + (size_t)(h * 128 + row) * NS + kbase + ((p ^ (row & 7)) << 3),
              (char*)Vs + (i * 4 + w) * 1024);
    }
    __syncthreads();

    // S = Q K^T : per-wave 16x64 in 4 f32x4
    f32x4 sa[4] = {};
    __builtin_amdgcn_s_setprio(1);
    #pragma unroll
    for (int f = 0; f < 6; ++f) {
      #pragma unroll
      for (int n = 0; n < 4; ++n) {
        const int row = n * 16 + r16;
        const int s = f * 4 + g;
        const int phys = (s & ~7) | ((s & 7) ^ (row & 7));
        short8 bg = Ks[row * KSL + phys];
        sa[n] = __builtin_amdgcn_mfma_f32_16x16x32_bf16(aq[f], bg, sa[n], 0, 0, 0);
      }
    }
    __builtin_amdgcn_s_setprio(0);

    // online softmax with defer-max (skip O-rescale when max grew < 8)
    const bool diag = (kt == qt);
    float pj[4][4];
    #pragma unroll
    for (int n = 0; n < 4; ++n) {
      const int key = kbase + n * 16 + r16;
      #pragma unroll
      for (int j = 0; j < 4; ++j) {
        float v = sa[n][j] * ATT_SCALE;
        if (diag && key > (qrow0 + g * 4 + j)) v = -1e30f;
        pj[n][j] = v;
      }
    }
    float mx4[4];
    float needf = 0.f;
    #pragma unroll
    for (int j = 0; j < 4; ++j) {
      float mx = fmaxf(fmaxf(pj[0][j], pj[1][j]), fmaxf(pj[2][j], pj[3][j]));
      #pragma unroll
      for (int o2 = 1; o2 < 16; o2 <<= 1) mx = fmaxf(mx, __shfl_xor(mx, o2, 64));
      mx4[j] = mx;
      needf += (mx > m_j[j] + 8.f) ? 1.f : 0.f;
    }
    const bool need = __any(needf > 0.f);
    #pragma unroll
    for (int j = 0; j < 4; ++j) {
      if (need) {
        const float mn = fmaxf(m_j[j], mx4[j]);
        const float c = __expf(m_j[j] - mn);
        l_j[j] *= c;
        #pragma unroll
        for (int n8 = 0; n8 < 8; ++n8) o[n8][j] *= c;
        m_j[j] = mn;
      }
      float rs = 0.f;
      #pragma unroll
      for (int n = 0; n < 4; ++n) {
        float p = __expf(pj[n][j] - m_j[j]);
        pj[n][j] = p;
        rs += p;
      }
      #pragma unroll
      for (int o2 = 1; o2 < 16; o2 <<= 1) rs += __shfl_xor(rs, o2, 64);
      l_j[j] += rs;
      const int prow = w * 16 + g * 4 + j;
      #pragma unroll
      for (int n = 0; n < 4; ++n)
        Pl[prow * PLS + n * 16 + r16] = f2b(pj[n][j]);
    }

    // O += P V : vb = Vs[d][ (kk*4+g) ^ (d&7) ]  (d = n8*16+r16)
    #pragma unroll
    for (int kk = 0; kk < 2; ++kk) {
      short8 pa = *(const short8*)&Pl[(w * 16 + r16) * PLS + kk * 32 + g * 8];
      __builtin_amdgcn_s_setprio(1);
      #pragma unroll
      for (int n8 = 0; n8 < 8; ++n8) {
        short8 vb = Vs[(n8 * 16 + r16) * 8 + ((kk * 4 + g) ^ (r16 & 7))];
        o[n8] = __builtin_amdgcn_mfma_f32_16x16x32_bf16(pa, vb, o[n8], 0, 0, 0);
      }
      __builtin_amdgcn_s_setprio(0);
    }
    __syncthreads();
  }

  #pragma unroll
  for (int j = 0; j < 4; ++j) {
    const float inv = 1.0f / l_j[j];
    const size_t rowoff = (size_t)(qrow0 + g * 4 + j) * OW + h * DVAL;
    #pragma unroll
    for (int n8 = 0; n8 < 8; ++n8)
      att[rowoff + n8 * 16 + r16] = f2b(o[n8][j] * inv);
  }
}

extern "C" void kernel_launch(void* const* d_in, const int* in_sizes, int n_in,
                              void* d_out, int out_size, void* d_ws, size_t ws_size,
                              hipStream_t stream) {
  const float* x      = (const float*)d_in[0];
  const float* wq     = (const float*)d_in[1];
  const float* wkv_a  = (const float*)d_in[2];
  const float* w_norm = (const float*)d_in[3];
  const float* wkv_b  = (const float*)d_in[4];
  const float* wo     = (const float*)d_in[5];
  float* out = (float*)d_out;

  unsigned short* wqT   = (unsigned short*)d_ws;
  unsigned short* wkvaT = wqT   + (long)QW * ND;
  unsigned short* wkvbT = wkvaT + (long)AWPAD * ND;
  unsigned short* woT   = wkvbT + (long)BW * RANK;
  unsigned short* xb    = woT   + (long)ND * OW;   // 2048x2048; dead after kva-gemm
  unsigned short* q     = xb    + (long)NS * ND;
  unsigned short* kva   = q     + (long)NS * QW;
  unsigned short* kvb   = kva   + (long)NS * AW;
  unsigned short* att   = kvb   + (long)NS * BW;
  unsigned short* vT    = xb;                      // alias: vT[2048][NS] reuses xb

  k_transpose<<<dim3(ND / 32, QW / 32),    dim3(256), 0, stream>>>(wq,    wqT,   ND,  QW);
  k_transpose<<<dim3(ND / 32, AWPAD / 32), dim3(256), 0, stream>>>(wkv_a, wkvaT, ND,  AW);
  k_transpose<<<dim3(RANK / 32, BW / 32),  dim3(256), 0, stream>>>(wkv_b, wkvbT, RANK, BW);
  k_transpose<<<dim3(OW / 32, ND / 32),    dim3(256), 0, stream>>>(wo,    woT,   OW,  ND);

  for (int b = 0; b < NB; ++b) {
    const float* xf = x + (long)b * NS * ND;
    float* outb = out + (long)b * NS * ND;
    k_cvt<<<dim3((NS * ND) / 1024), dim3(256), 0, stream>>>(xf, xb);
    gemm_bf16<unsigned short, false><<<dim3(QW / 128, NS / 128), dim3(256), 0, stream>>>(
        xb, wqT, q, nullptr, NS, QW, ND, ND);
    gemm_bf16<unsigned short, false><<<dim3(5 * 8 / 8, 0 ? 0 : NS / 128), dim3(256), 0, stream>>>(
        xb, wkvaT, kva, nullptr, NS, AW, ND, ND);
    k_rms_b<<<dim3(NS), dim3(256), 0, stream>>>(kva, w_norm);
    k_ropek_b<<<dim3(NS), dim3(64), 0, stream>>>(kva);
    k_ropeq_b<<<dim3(NS), dim3(512), 0, stream>>>(q);
    // kvb + transposed V epilogue (writes vT, aliased onto xb which is now dead)
    gemm_bf16<unsigned short, true><<<dim3(BW / 128, NS / 128), dim3(256), 0, stream>>>(
        kva, wkvbT, kvb, vT, NS, BW, RANK, AW);
    k_attn_mfma<<<dim3(NS / QBLK, NH), dim3(256), 0, stream>>>(q, kvb, kva, vT, att);
    gemm_bf16<float, false><<<dim3(ND / 128, NS / 128), dim3(256), 0, stream>>>(
        att, woT, outb, nullptr, NS, ND, OW, OW);
  }
}

// Round 11
// 361.167 us; speedup vs baseline: 1.8882x; 1.8882x over previous
//
#include <hip/hip_runtime.h>
#include <hip/hip_bf16.h>
#include <math.h>

#define NB 2
#define NS 2048
#define ND 2048
#define NH 16
#define DNOPE 128
#define DROPE 64
#define DVAL 128
#define RANK 512
#define QW (NH*(DNOPE+DROPE))    // 3072
#define AW (RANK+DROPE)          // 576
#define AWPAD 640
#define BW (NH*(DNOPE+DVAL))     // 4096
#define OW (NH*DVAL)             // 2048
#define ATT_SCALE 0.07216878364870322f

typedef __attribute__((ext_vector_type(8))) short short8;
typedef __attribute__((ext_vector_type(4))) float f32x4;

__device__ __forceinline__ float b2f(unsigned short u) {
  unsigned x = ((unsigned)u) << 16; float f; __builtin_memcpy(&f, &x, 4); return f;
}
__device__ __forceinline__ unsigned short f2b(float f) {
  unsigned x; __builtin_memcpy(&x, &f, 4);
  unsigned r = (x + 0x7fffu + ((x >> 16) & 1u)) >> 16;
  return (unsigned short)r;
}
__device__ __forceinline__ void gload16(const void* g, void* lds) {
  __builtin_amdgcn_global_load_lds((const __attribute__((address_space(1))) void*)g,
                                   (__attribute__((address_space(3))) void*)lds, 16, 0, 0);
}

// ---------- fp32 -> bf16 flat convert ----------
__global__ __launch_bounds__(256) void k_cvt(const float* __restrict__ X,
                                             unsigned short* __restrict__ Y) {
  long i = ((long)blockIdx.x * 256 + threadIdx.x) * 4;
  float4 v = *(const float4*)(X + i);
  ushort4 o;
  o.x = f2b(v.x); o.y = f2b(v.y); o.z = f2b(v.z); o.w = f2b(v.w);
  *(ushort4*)(Y + i) = o;
}

// ---------- transpose+convert: W fp32 [K][N] -> WT bf16 [Npad][K], zero pad ----------
__global__ __launch_bounds__(256) void k_transpose(const float* __restrict__ W,
                                                   unsigned short* __restrict__ WT,
                                                   int K, int N) {
  __shared__ float t[32][33];
  const int k0 = blockIdx.x * 32, n0 = blockIdx.y * 32;
  const int tx = threadIdx.x & 31, ty = threadIdx.x >> 5;
  #pragma unroll
  for (int i = 0; i < 32; i += 8) {
    int n = n0 + tx;
    float v = (n < N) ? W[(size_t)(k0 + ty + i) * N + n] : 0.f;
    t[ty + i][tx] = v;
  }
  __syncthreads();
  #pragma unroll
  for (int i = 0; i < 32; i += 8)
    WT[(size_t)(n0 + ty + i) * K + k0 + tx] = f2b(t[tx][ty + i]);
}

// ---------- bf16 MFMA GEMM (validated round 6; + XCD swizzle) ----------
template <typename OutT>
__global__ __launch_bounds__(256) void gemm_bf16(
    const unsigned short* __restrict__ A, const unsigned short* __restrict__ BT,
    OutT* __restrict__ C, int M, int N, int K, int lda) {
  __shared__ short8 AsV[1024];
  __shared__ short8 BsV[1024];
  const int tid = threadIdx.x;
  const int l = tid & 63, w = tid >> 6;
  const int nwg = gridDim.x * gridDim.y;
  const int bid = blockIdx.y * gridDim.x + blockIdx.x;
  const int sbid = (bid & 7) * (nwg >> 3) + (bid >> 3);
  const int bx = sbid % gridDim.x, by = sbid / gridDim.x;
  const int bm = by * 128, bn = bx * 128;
  const int wm = (w >> 1) * 64, wn = (w & 1) * 64;
  f32x4 acc[4][4] = {};

  const int srow = tid >> 3;
  const int gk   = ((((tid & 7) * 16) ^ ((srow & 7) << 4)) >> 1);
  const int sw   = l & 7;

  for (int k0 = 0; k0 < K; k0 += 64) {
    #pragma unroll
    for (int i = 0; i < 4; ++i) {
      const int row = i * 32 + srow;
      gload16(A + (size_t)(bm + row) * lda + k0 + gk, (char*)AsV + i * 4096 + w * 1024);
      gload16(BT + (size_t)(bn + row) * K   + k0 + gk, (char*)BsV + i * 4096 + w * 1024);
    }
    __syncthreads();
    #pragma unroll
    for (int kk2 = 0; kk2 < 2; ++kk2) {
      const int kb = kk2 * 4 + (l >> 4);
      short8 af[4], bg[4];
      #pragma unroll
      for (int mi = 0; mi < 4; ++mi)
        af[mi] = AsV[(wm + mi * 16 + (l & 15)) * 8 + (kb ^ sw)];
      #pragma unroll
      for (int ni = 0; ni < 4; ++ni)
        bg[ni] = BsV[(wn + ni * 16 + (l & 15)) * 8 + (kb ^ sw)];
      #pragma unroll
      for (int mi = 0; mi < 4; ++mi)
        #pragma unroll
        for (int ni = 0; ni < 4; ++ni)
          acc[mi][ni] = __builtin_amdgcn_mfma_f32_16x16x32_bf16(af[mi], bg[ni], acc[mi][ni], 0, 0, 0);
    }
    __syncthreads();
  }

  const int r0 = bm + wm + (l >> 4) * 4;
  const int c0 = bn + wn + (l & 15);
  #pragma unroll
  for (int mi = 0; mi < 4; ++mi)
    #pragma unroll
    for (int ni = 0; ni < 4; ++ni) {
      const int col = c0 + ni * 16;
      if (col < N) {
        #pragma unroll
        for (int j = 0; j < 4; ++j) {
          float v = acc[mi][ni][j];
          if constexpr (__is_same(OutT, float))
            C[(size_t)(r0 + mi * 16 + j) * N + col] = v;
          else
            C[(size_t)(r0 + mi * 16 + j) * N + col] = f2b(v);
        }
      }
    }
}

// ---------- RMSNorm on bf16 kva rows (both batches: grid 4096) ----------
__global__ __launch_bounds__(256) void k_rms_b(unsigned short* __restrict__ kva,
                                               const float* __restrict__ w) {
  const int row = blockIdx.x;
  unsigned short* p = kva + (long)row * AW;
  __shared__ float sd[256];
  float ss = 0.f;
  for (int j = threadIdx.x; j < RANK; j += 256) { float v = b2f(p[j]); ss += v * v; }
  sd[threadIdx.x] = ss;
  __syncthreads();
  for (int st = 128; st > 0; st >>= 1) {
    if (threadIdx.x < st) sd[threadIdx.x] += sd[threadIdx.x + st];
    __syncthreads();
  }
  const float sc = rsqrtf(sd[0] / (float)RANK + 1e-6f);
  for (int j = threadIdx.x; j < RANK; j += 256) p[j] = f2b(b2f(p[j]) * sc * w[j]);
}

// ---------- RoPE k_pe (batch-local position = row & (NS-1)) ----------
__global__ __launch_bounds__(64) void k_ropek_b(unsigned short* __restrict__ kva) {
  const int row = blockIdx.x;
  const int t = row & (NS - 1);
  const int i = threadIdx.x;
  if (i >= 32) return;
  const double invf = pow(10000.0, -(double)i / 32.0);
  const double ang = (double)t * invf;
  const float c = (float)cos(ang), s = (float)sin(ang);
  unsigned short* p = kva + (long)row * AW + RANK + 2 * i;
  const float x0 = b2f(p[0]), x1 = b2f(p[1]);
  p[0] = f2b(x0 * c - x1 * s);
  p[1] = f2b(x0 * s + x1 * c);
}

// ---------- RoPE q_pe (batch-local position) ----------
__global__ __launch_bounds__(512) void k_ropeq_b(unsigned short* __restrict__ q) {
  const int row = blockIdx.x;
  const int t = row & (NS - 1);
  const int h = threadIdx.x >> 5;
  const int i = threadIdx.x & 31;
  const double invf = pow(10000.0, -(double)i / 32.0);
  const double ang = (double)t * invf;
  const float c = (float)cos(ang), s = (float)sin(ang);
  unsigned short* p = q + (long)row * QW + h * (DNOPE + DROPE) + DNOPE + 2 * i;
  const float x0 = b2f(p[0]), x1 = b2f(p[1]);
  p[0] = f2b(x0 * c - x1 * s);
  p[1] = f2b(x0 * s + x1 * c);
}

// ---------- MFMA flash attention, balanced q-tile pairs ----------
// grid (8, NH, NB), 512 thr = 8 waves x 16 rows = 128 q-rows per phase.
// Block handles q-tiles bx and 15-bx sequentially: (2bx+2)+(32-2bx) = 34 k-tiles, constant.
#define KBLK 64
#define KSL 24               // 16B slots per K row (192 bf16)
#define VTS 72               // VT row stride (elems)
#define PLS 72               // P row stride (elems)
#define QTILES (NS/128)      // 16
__global__ __launch_bounds__(512) void k_attn_mfma(
    const unsigned short* __restrict__ qg,
    const unsigned short* __restrict__ kvbg,
    const unsigned short* __restrict__ kvag,
    unsigned short* __restrict__ attg) {
  __shared__ short8 Ks[KBLK * KSL];                        // 24 KB, slot-swizzled
  __shared__ __align__(16) unsigned short VT[DVAL * VTS];  // 18 KB, V transposed
  __shared__ __align__(16) unsigned short Pl[128 * PLS];   // 18 KB
  const int tid = threadIdx.x;
  const int l = tid & 63, w = tid >> 6;    // w 0..7
  const int g = l >> 4, r16 = l & 15;
  const int h = blockIdx.y;
  const int b = blockIdx.z;
  const unsigned short* q   = qg   + (size_t)b * NS * QW;
  const unsigned short* kvb = kvbg + (size_t)b * NS * BW;
  const unsigned short* kva = kvag + (size_t)b * NS * AW;
  unsigned short* att = attg + (size_t)b * NS * OW;

  #pragma unroll 1
  for (int phase = 0; phase < 2; ++phase) {
    const int qt = phase ? (QTILES - 1 - (int)blockIdx.x) : (int)blockIdx.x;
    const int nt = 2 * qt + 2;
    const int qrow0 = qt * 128 + w * 16;

    // Q A-frags: 16 rows x 192, resident in registers
    short8 aq[6];
    {
      const unsigned short* qp = q + (size_t)(qrow0 + r16) * QW + h * 192 + g * 8;
      #pragma unroll
      for (int f = 0; f < 6; ++f) aq[f] = *(const short8*)(qp + f * 32);
    }
    f32x4 o[8] = {};
    float m_j[4], l_j[4];
    #pragma unroll
    for (int j = 0; j < 4; ++j) { m_j[j] = -1e30f; l_j[j] = 0.f; }

    for (int kt = 0; kt < nt; ++kt) {
      const int kbase = kt * KBLK;
      // stage K (64x192) swizzled: 1536 chunks / 512 thr = 3 issues
      #pragma unroll
      for (int i = 0; i < 3; ++i) {
        const int chunk = i * 512 + tid;
        const int row = chunk / KSL, p = chunk % KSL;
        const int s = (p & ~7) | ((p & 7) ^ (row & 7));
        const int d0 = s * 8;
        const unsigned short* src =
            (d0 < DNOPE) ? kvb + (size_t)(kbase + row) * BW + h * 256 + d0
                         : kva + (size_t)(kbase + row) * AW + RANK + (d0 - DNOPE);
        gload16(src, (char*)Ks + (size_t)(i * 512 + (tid & ~63)) * 16);
      }
      // stage V^T (VT[d][t]) with rotated write order (bank spread)
      {
        const int t = tid >> 3;
        const int qd = tid & 7;
        #pragma unroll
        for (int pass = 0; pass < 2; ++pass) {
          const int d0 = qd * 8 + pass * 64;
          short8 v = *(const short8*)(kvb + (size_t)(kbase + t) * BW + h * 256 + DNOPE + d0);
          #pragma unroll
          for (int jj = 0; jj < 8; ++jj) {
            const int jr = (jj + qd) & 7;
            VT[(d0 + jr) * VTS + t] = (unsigned short)v[jr];
          }
        }
      }
      __syncthreads();

      // S = Q K^T : per-wave 16x64 in 4 f32x4
      f32x4 sa[4] = {};
      __builtin_amdgcn_s_setprio(1);
      #pragma unroll
      for (int f = 0; f < 6; ++f) {
        #pragma unroll
        for (int n = 0; n < 4; ++n) {
          const int row = n * 16 + r16;
          const int s = f * 4 + g;
          const int phys = (s & ~7) | ((s & 7) ^ (row & 7));
          short8 bg = Ks[row * KSL + phys];
          sa[n] = __builtin_amdgcn_mfma_f32_16x16x32_bf16(aq[f], bg, sa[n], 0, 0, 0);
        }
      }
      __builtin_amdgcn_s_setprio(0);

      // online softmax with defer-max
      const bool diag = (kt == nt - 1) || (kt == nt - 2);
      float pj[4][4];
      #pragma unroll
      for (int n = 0; n < 4; ++n) {
        const int key = kbase + n * 16 + r16;
        #pragma unroll
        for (int j = 0; j < 4; ++j) {
          float v = sa[n][j] * ATT_SCALE;
          if (diag && key > (qrow0 + g * 4 + j)) v = -1e30f;
          pj[n][j] = v;
        }
      }
      float mx4[4];
      float needf = 0.f;
      #pragma unroll
      for (int j = 0; j < 4; ++j) {
        float mx = fmaxf(fmaxf(pj[0][j], pj[1][j]), fmaxf(pj[2][j], pj[3][j]));
        #pragma unroll
        for (int o2 = 1; o2 < 16; o2 <<= 1) mx = fmaxf(mx, __shfl_xor(mx, o2, 64));
        mx4[j] = mx;
        needf += (mx > m_j[j] + 8.f) ? 1.f : 0.f;
      }
      const bool need = __any(needf > 0.f);
      #pragma unroll
      for (int j = 0; j < 4; ++j) {
        if (need) {
          const float mn = fmaxf(m_j[j], mx4[j]);
          const float c = __expf(m_j[j] - mn);
          l_j[j] *= c;
          #pragma unroll
          for (int n8 = 0; n8 < 8; ++n8) o[n8][j] *= c;
          m_j[j] = mn;
        }
        float rs = 0.f;
        #pragma unroll
        for (int n = 0; n < 4; ++n) {
          float p = __expf(pj[n][j] - m_j[j]);
          pj[n][j] = p;
          rs += p;
        }
        #pragma unroll
        for (int o2 = 1; o2 < 16; o2 <<= 1) rs += __shfl_xor(rs, o2, 64);
        l_j[j] += rs;
        const int prow = w * 16 + g * 4 + j;
        #pragma unroll
        for (int n = 0; n < 4; ++n)
          Pl[prow * PLS + n * 16 + r16] = f2b(pj[n][j]);
      }

      // O += P V (own wave's P rows; VT shared)
      #pragma unroll
      for (int kk = 0; kk < 2; ++kk) {
        short8 pa = *(const short8*)&Pl[(w * 16 + r16) * PLS + kk * 32 + g * 8];
        __builtin_amdgcn_s_setprio(1);
        #pragma unroll
        for (int n8 = 0; n8 < 8; ++n8) {
          short8 vb = *(const short8*)&VT[(n8 * 16 + r16) * VTS + kk * 32 + g * 8];
          o[n8] = __builtin_amdgcn_mfma_f32_16x16x32_bf16(pa, vb, o[n8], 0, 0, 0);
        }
        __builtin_amdgcn_s_setprio(0);
      }
      __syncthreads();
    }

    #pragma unroll
    for (int j = 0; j < 4; ++j) {
      const float inv = 1.0f / l_j[j];
      const size_t rowoff = (size_t)(qrow0 + g * 4 + j) * OW + h * DVAL;
      #pragma unroll
      for (int n8 = 0; n8 < 8; ++n8)
        att[rowoff + n8 * 16 + r16] = f2b(o[n8][j] * inv);
    }
  }
}

extern "C" void kernel_launch(void* const* d_in, const int* in_sizes, int n_in,
                              void* d_out, int out_size, void* d_ws, size_t ws_size,
                              hipStream_t stream) {
  const float* x      = (const float*)d_in[0];
  const float* wq     = (const float*)d_in[1];
  const float* wkv_a  = (const float*)d_in[2];
  const float* w_norm = (const float*)d_in[3];
  const float* wkv_b  = (const float*)d_in[4];
  const float* wo     = (const float*)d_in[5];
  float* out = (float*)d_out;

  // ws layout (shorts), both batches live; att2 aliases xb2 (dead by then). ~108 MB.
  unsigned short* wqT   = (unsigned short*)d_ws;           // 3072 x 2048
  unsigned short* wkvaT = wqT   + (long)QW * ND;           // 640  x 2048
  unsigned short* wkvbT = wkvaT + (long)AWPAD * ND;        // 4096 x 512
  unsigned short* woT   = wkvbT + (long)BW * RANK;         // 2048 x 2048
  unsigned short* xb2   = woT   + (long)ND * OW;           // 2 x 2048 x 2048
  unsigned short* q2    = xb2   + (long)NB * NS * ND;      // 2 x 2048 x 3072
  unsigned short* kva2  = q2    + (long)NB * NS * QW;      // 2 x 2048 x 576
  unsigned short* kvb2  = kva2  + (long)NB * NS * AW;      // 2 x 2048 x 4096
  unsigned short* att2  = xb2;                             // alias

  k_transpose<<<dim3(ND / 32, QW / 32),    dim3(256), 0, stream>>>(wq,    wqT,   ND,  QW);
  k_transpose<<<dim3(ND / 32, AWPAD / 32), dim3(256), 0, stream>>>(wkv_a, wkvaT, ND,  AW);
  k_transpose<<<dim3(RANK / 32, BW / 32),  dim3(256), 0, stream>>>(wkv_b, wkvbT, RANK, BW);
  k_transpose<<<dim3(OW / 32, ND / 32),    dim3(256), 0, stream>>>(wo,    woT,   OW,  ND);

  // convert both batches of x
  k_cvt<<<dim3((NB * NS * ND) / 1024), dim3(256), 0, stream>>>(x, xb2);
  // q2 = x @ wq  (M = 4096)
  gemm_bf16<unsigned short><<<dim3(QW / 128, (NB * NS) / 128), dim3(256), 0, stream>>>(
      xb2, wqT, q2, NB * NS, QW, ND, ND);
  // kva2 = x @ wkv_a
  gemm_bf16<unsigned short><<<dim3(5, (NB * NS) / 128), dim3(256), 0, stream>>>(
      xb2, wkvaT, kva2, NB * NS, AW, ND, ND);
  k_rms_b<<<dim3(NB * NS), dim3(256), 0, stream>>>(kva2, w_norm);
  k_ropek_b<<<dim3(NB * NS), dim3(64), 0, stream>>>(kva2);
  k_ropeq_b<<<dim3(NB * NS), dim3(512), 0, stream>>>(q2);
  // kvb2 = kv_n @ wkv_b
  gemm_bf16<unsigned short><<<dim3(BW / 128, (NB * NS) / 128), dim3(256), 0, stream>>>(
      kva2, wkvbT, kvb2, NB * NS, BW, RANK, AW);
  // attention, both batches, balanced blocks (xb2 dead -> att2 alias safe)
  k_attn_mfma<<<dim3(8, NH, NB), dim3(512), 0, stream>>>(q2, kvb2, kva2, att2);
  // out = att @ wo (fp32, M = 4096)
  gemm_bf16<float><<<dim3(ND / 128, (NB * NS) / 128), dim3(256), 0, stream>>>(
      att2, woT, out, NB * NS, ND, OW, OW);
}

// Round 12
// 352.377 us; speedup vs baseline: 1.9353x; 1.0249x over previous
//
#include <hip/hip_runtime.h>
#include <hip/hip_bf16.h>
#include <math.h>

#define NB 2
#define NS 2048
#define ND 2048
#define NH 16
#define DNOPE 128
#define DROPE 64
#define DVAL 128
#define RANK 512
#define QW (NH*(DNOPE+DROPE))    // 3072
#define AW (RANK+DROPE)          // 576
#define AWPAD 640
#define BW (NH*(DNOPE+DVAL))     // 4096
#define OW (NH*DVAL)             // 2048
#define ATT_SCALE 0.07216878364870322f
#define ATT_SCALE2 0.10411758590510176f   // ATT_SCALE * log2(e)

typedef __attribute__((ext_vector_type(8))) short short8;
typedef __attribute__((ext_vector_type(4))) float f32x4;

__device__ __forceinline__ float b2f(unsigned short u) {
  unsigned x = ((unsigned)u) << 16; float f; __builtin_memcpy(&f, &x, 4); return f;
}
__device__ __forceinline__ unsigned short f2b(float f) {
  unsigned x; __builtin_memcpy(&x, &f, 4);
  unsigned r = (x + 0x7fffu + ((x >> 16) & 1u)) >> 16;
  return (unsigned short)r;
}
__device__ __forceinline__ unsigned cvtpk(float a, float b) {
  unsigned r;
  asm("v_cvt_pk_bf16_f32 %0, %1, %2" : "=v"(r) : "v"(a), "v"(b));
  return r;
}
__device__ __forceinline__ void gload16(const void* g, void* lds) {
  __builtin_amdgcn_global_load_lds((const __attribute__((address_space(1))) void*)g,
                                   (__attribute__((address_space(3))) void*)lds, 16, 0, 0);
}

// ---------- fp32 -> bf16 flat convert ----------
__global__ __launch_bounds__(256) void k_cvt(const float* __restrict__ X,
                                             unsigned short* __restrict__ Y) {
  long i = ((long)blockIdx.x * 256 + threadIdx.x) * 4;
  float4 v = *(const float4*)(X + i);
  ushort4 o;
  o.x = f2b(v.x); o.y = f2b(v.y); o.z = f2b(v.z); o.w = f2b(v.w);
  *(ushort4*)(Y + i) = o;
}

// ---------- transpose+convert: W fp32 [K][N] -> WT bf16 [Npad][K], zero pad ----------
__global__ __launch_bounds__(256) void k_transpose(const float* __restrict__ W,
                                                   unsigned short* __restrict__ WT,
                                                   int K, int N) {
  __shared__ float t[32][33];
  const int k0 = blockIdx.x * 32, n0 = blockIdx.y * 32;
  const int tx = threadIdx.x & 31, ty = threadIdx.x >> 5;
  #pragma unroll
  for (int i = 0; i < 32; i += 8) {
    int n = n0 + tx;
    float v = (n < N) ? W[(size_t)(k0 + ty + i) * N + n] : 0.f;
    t[ty + i][tx] = v;
  }
  __syncthreads();
  #pragma unroll
  for (int i = 0; i < 32; i += 8)
    WT[(size_t)(n0 + ty + i) * K + k0 + tx] = f2b(t[tx][ty + i]);
}

// ---------- bf16 MFMA GEMM (validated round 6; + XCD swizzle) ----------
template <typename OutT>
__global__ __launch_bounds__(256) void gemm_bf16(
    const unsigned short* __restrict__ A, const unsigned short* __restrict__ BT,
    OutT* __restrict__ C, int M, int N, int K, int lda) {
  __shared__ short8 AsV[1024];
  __shared__ short8 BsV[1024];
  const int tid = threadIdx.x;
  const int l = tid & 63, w = tid >> 6;
  const int nwg = gridDim.x * gridDim.y;
  const int bid = blockIdx.y * gridDim.x + blockIdx.x;
  const int sbid = (bid & 7) * (nwg >> 3) + (bid >> 3);
  const int bx = sbid % gridDim.x, by = sbid / gridDim.x;
  const int bm = by * 128, bn = bx * 128;
  const int wm = (w >> 1) * 64, wn = (w & 1) * 64;
  f32x4 acc[4][4] = {};

  const int srow = tid >> 3;
  const int gk   = ((((tid & 7) * 16) ^ ((srow & 7) << 4)) >> 1);
  const int sw   = l & 7;

  for (int k0 = 0; k0 < K; k0 += 64) {
    #pragma unroll
    for (int i = 0; i < 4; ++i) {
      const int row = i * 32 + srow;
      gload16(A + (size_t)(bm + row) * lda + k0 + gk, (char*)AsV + i * 4096 + w * 1024);
      gload16(BT + (size_t)(bn + row) * K   + k0 + gk, (char*)BsV + i * 4096 + w * 1024);
    }
    __syncthreads();
    #pragma unroll
    for (int kk2 = 0; kk2 < 2; ++kk2) {
      const int kb = kk2 * 4 + (l >> 4);
      short8 af[4], bg[4];
      #pragma unroll
      for (int mi = 0; mi < 4; ++mi)
        af[mi] = AsV[(wm + mi * 16 + (l & 15)) * 8 + (kb ^ sw)];
      #pragma unroll
      for (int ni = 0; ni < 4; ++ni)
        bg[ni] = BsV[(wn + ni * 16 + (l & 15)) * 8 + (kb ^ sw)];
      #pragma unroll
      for (int mi = 0; mi < 4; ++mi)
        #pragma unroll
        for (int ni = 0; ni < 4; ++ni)
          acc[mi][ni] = __builtin_amdgcn_mfma_f32_16x16x32_bf16(af[mi], bg[ni], acc[mi][ni], 0, 0, 0);
    }
    __syncthreads();
  }

  const int r0 = bm + wm + (l >> 4) * 4;
  const int c0 = bn + wn + (l & 15);
  #pragma unroll
  for (int mi = 0; mi < 4; ++mi)
    #pragma unroll
    for (int ni = 0; ni < 4; ++ni) {
      const int col = c0 + ni * 16;
      if (col < N) {
        #pragma unroll
        for (int j = 0; j < 4; ++j) {
          float v = acc[mi][ni][j];
          if constexpr (__is_same(OutT, float))
            C[(size_t)(r0 + mi * 16 + j) * N + col] = v;
          else
            C[(size_t)(r0 + mi * 16 + j) * N + col] = f2b(v);
        }
      }
    }
}

// ---------- RMSNorm on bf16 kva rows (both batches: grid 4096) ----------
__global__ __launch_bounds__(256) void k_rms_b(unsigned short* __restrict__ kva,
                                               const float* __restrict__ w) {
  const int row = blockIdx.x;
  unsigned short* p = kva + (long)row * AW;
  __shared__ float sd[256];
  float ss = 0.f;
  for (int j = threadIdx.x; j < RANK; j += 256) { float v = b2f(p[j]); ss += v * v; }
  sd[threadIdx.x] = ss;
  __syncthreads();
  for (int st = 128; st > 0; st >>= 1) {
    if (threadIdx.x < st) sd[threadIdx.x] += sd[threadIdx.x + st];
    __syncthreads();
  }
  const float sc = rsqrtf(sd[0] / (float)RANK + 1e-6f);
  for (int j = threadIdx.x; j < RANK; j += 256) p[j] = f2b(b2f(p[j]) * sc * w[j]);
}

// ---------- RoPE k_pe (batch-local position = row & (NS-1)) ----------
__global__ __launch_bounds__(64) void k_ropek_b(unsigned short* __restrict__ kva) {
  const int row = blockIdx.x;
  const int t = row & (NS - 1);
  const int i = threadIdx.x;
  if (i >= 32) return;
  const double invf = pow(10000.0, -(double)i / 32.0);
  const double ang = (double)t * invf;
  const float c = (float)cos(ang), s = (float)sin(ang);
  unsigned short* p = kva + (long)row * AW + RANK + 2 * i;
  const float x0 = b2f(p[0]), x1 = b2f(p[1]);
  p[0] = f2b(x0 * c - x1 * s);
  p[1] = f2b(x0 * s + x1 * c);
}

// ---------- RoPE q_pe (batch-local position) ----------
__global__ __launch_bounds__(512) void k_ropeq_b(unsigned short* __restrict__ q) {
  const int row = blockIdx.x;
  const int t = row & (NS - 1);
  const int h = threadIdx.x >> 5;
  const int i = threadIdx.x & 31;
  const double invf = pow(10000.0, -(double)i / 32.0);
  const double ang = (double)t * invf;
  const float c = (float)cos(ang), s = (float)sin(ang);
  unsigned short* p = q + (long)row * QW + h * (DNOPE + DROPE) + DNOPE + 2 * i;
  const float x0 = b2f(p[0]), x1 = b2f(p[1]);
  p[0] = f2b(x0 * c - x1 * s);
  p[1] = f2b(x0 * s + x1 * c);
}

// ---------- MFMA flash attention, balanced q-tile pairs ----------
// grid (8, NH, NB), 512 thr = 8 waves x 16 rows = 128 q-rows per phase.
// Block handles q-tiles bx and 15-bx sequentially -> constant 34 k-tiles/block.
// V^T LDS layout XOR-swizzled: VT[d][ t ^ ((d>>3 & 7)<<3) ] -> conflict-free writes.
#define KBLK 64
#define KSL 24               // 16B slots per K row (192 bf16)
#define VTS 72               // VT row stride (elems)
#define PLS 72               // P row stride (elems)
#define QTILES (NS/128)      // 16
__global__ __launch_bounds__(512) void k_attn_mfma(
    const unsigned short* __restrict__ qg,
    const unsigned short* __restrict__ kvbg,
    const unsigned short* __restrict__ kvag,
    unsigned short* __restrict__ attg) {
  __shared__ short8 Ks[KBLK * KSL];                        // 24 KB, slot-swizzled
  __shared__ __align__(16) unsigned short VT[DVAL * VTS];  // 18 KB, V^T XOR-swizzled
  __shared__ __align__(16) unsigned short Pl[128 * PLS];   // 18 KB
  const int tid = threadIdx.x;
  const int l = tid & 63, w = tid >> 6;    // w 0..7
  const int g = l >> 4, r16 = l & 15;
  const int h = blockIdx.y;
  const int b = blockIdx.z;
  const unsigned short* q   = qg   + (size_t)b * NS * QW;
  const unsigned short* kvb = kvbg + (size_t)b * NS * BW;
  const unsigned short* kva = kvag + (size_t)b * NS * AW;
  unsigned short* att = attg + (size_t)b * NS * OW;

  // ---- staging geometry, constant per thread (hoisted out of k-loop) ----
  // K: 3 gload16 issues
  const unsigned short* kbs[3]; int kstp[3]; char* kdst[3];
  #pragma unroll
  for (int i = 0; i < 3; ++i) {
    const int chunk = i * 512 + tid;
    const int row = chunk / KSL, p = chunk % KSL;
    const int s = (p & ~7) | ((p & 7) ^ (row & 7));
    const int d0 = s * 8;
    if (d0 < DNOPE) { kbs[i] = kvb + (size_t)row * BW + h * 256 + d0; kstp[i] = KBLK * BW; }
    else            { kbs[i] = kva + (size_t)row * AW + RANK + (d0 - DNOPE); kstp[i] = KBLK * AW; }
    kdst[i] = (char*)Ks + (size_t)(i * 512 + (tid & ~63)) * 16;
  }
  // V: thread -> t = tid>>3 (key), qd = tid&7 (d-octet); dest col' = t ^ (qd<<3)
  const int vt_t = tid >> 3, vqd = tid & 7;
  const unsigned short* vbs = kvb + (size_t)vt_t * BW + h * 256 + DNOPE + vqd * 8;
  unsigned short* vwd = VT + (vqd * 8) * VTS + (vt_t ^ (vqd << 3));

  #pragma unroll 1
  for (int phase = 0; phase < 2; ++phase) {
    const int qt = phase ? (QTILES - 1 - (int)blockIdx.x) : (int)blockIdx.x;
    const int nt = 2 * qt + 2;
    const int qrow0 = qt * 128 + w * 16;

    short8 aq[6];
    {
      const unsigned short* qp = q + (size_t)(qrow0 + r16) * QW + h * 192 + g * 8;
      #pragma unroll
      for (int f = 0; f < 6; ++f) aq[f] = *(const short8*)(qp + f * 32);
    }
    f32x4 o[8] = {};
    float m_j[4], l_j[4];
    #pragma unroll
    for (int j = 0; j < 4; ++j) { m_j[j] = -1e30f; l_j[j] = 0.f; }

    const unsigned short* kq0 = kbs[0];
    const unsigned short* kq1 = kbs[1];
    const unsigned short* kq2 = kbs[2];
    const unsigned short* vq  = vbs;

    for (int kt = 0; kt < nt; ++kt) {
      // stage K (pointer-march, zero index math)
      gload16(kq0, kdst[0]); kq0 += kstp[0];
      gload16(kq1, kdst[1]); kq1 += kstp[1];
      gload16(kq2, kdst[2]); kq2 += kstp[2];
      // stage V^T: static extracts, static offsets (XOR layout kills conflicts)
      #pragma unroll
      for (int pass = 0; pass < 2; ++pass) {
        short8 v = *(const short8*)(vq + pass * 64);
        unsigned short* base = vwd + pass * 64 * VTS;
        #pragma unroll
        for (int jj = 0; jj < 8; ++jj)
          base[jj * VTS] = (unsigned short)v[jj];
      }
      vq += KBLK * BW;
      __syncthreads();

      // S = Q K^T : per-wave 16x64 in 4 f32x4
      f32x4 sa[4] = {};
      __builtin_amdgcn_s_setprio(1);
      #pragma unroll
      for (int f = 0; f < 6; ++f) {
        #pragma unroll
        for (int n = 0; n < 4; ++n) {
          const int row = n * 16 + r16;
          const int s = f * 4 + g;
          const int phys = (s & ~7) | ((s & 7) ^ (row & 7));
          short8 bg = Ks[row * KSL + phys];
          sa[n] = __builtin_amdgcn_mfma_f32_16x16x32_bf16(aq[f], bg, sa[n], 0, 0, 0);
        }
      }
      __builtin_amdgcn_s_setprio(0);

      // online softmax in log2 domain, defer-max (threshold 8 -> P <= 256)
      const bool diag = (kt >= nt - 2);
      float pj[4][4];
      #pragma unroll
      for (int n = 0; n < 4; ++n) {
        const int key = kt * KBLK + n * 16 + r16;
        #pragma unroll
        for (int j = 0; j < 4; ++j) {
          float v = sa[n][j] * ATT_SCALE2;
          if (diag && key > (qrow0 + g * 4 + j)) v = -1e30f;
          pj[n][j] = v;
        }
      }
      float mx4[4];
      float needf = 0.f;
      #pragma unroll
      for (int j = 0; j < 4; ++j) {
        float mx = fmaxf(fmaxf(pj[0][j], pj[1][j]), fmaxf(pj[2][j], pj[3][j]));
        #pragma unroll
        for (int o2 = 1; o2 < 16; o2 <<= 1) mx = fmaxf(mx, __shfl_xor(mx, o2, 64));
        mx4[j] = mx;
        needf += (mx > m_j[j] + 8.f) ? 1.f : 0.f;
      }
      const bool need = __any(needf > 0.f);
      #pragma unroll
      for (int j = 0; j < 4; ++j) {
        if (need) {
          const float mn = fmaxf(m_j[j], mx4[j]);
          const float c = exp2f(m_j[j] - mn);
          l_j[j] *= c;
          #pragma unroll
          for (int n8 = 0; n8 < 8; ++n8) o[n8][j] *= c;
          m_j[j] = mn;
        }
        float rs = 0.f;
        #pragma unroll
        for (int n = 0; n < 4; ++n) {
          float p = exp2f(pj[n][j] - m_j[j]);
          pj[n][j] = p;
          rs += p;
        }
        #pragma unroll
        for (int o2 = 1; o2 < 16; o2 <<= 1) rs += __shfl_xor(rs, o2, 64);
        l_j[j] += rs;
        const int prow = w * 16 + g * 4 + j;
        const unsigned pk01 = cvtpk(pj[0][j], pj[1][j]);
        const unsigned pk23 = cvtpk(pj[2][j], pj[3][j]);
        Pl[prow * PLS +  0 + r16] = (unsigned short)pk01;
        Pl[prow * PLS + 16 + r16] = (unsigned short)(pk01 >> 16);
        Pl[prow * PLS + 32 + r16] = (unsigned short)pk23;
        Pl[prow * PLS + 48 + r16] = (unsigned short)(pk23 >> 16);
      }

      // O += P V : vb from XOR-swizzled VT
      const int hb = r16 >> 3;
      #pragma unroll
      for (int kk = 0; kk < 2; ++kk) {
        short8 pa = *(const short8*)&Pl[(w * 16 + r16) * PLS + kk * 32 + g * 8];
        __builtin_amdgcn_s_setprio(1);
        #pragma unroll
        for (int n8 = 0; n8 < 8; ++n8) {
          const int blk = (kk * 4 + g) ^ ((n8 * 2 + hb) & 7);
          short8 vb = *(const short8*)&VT[(n8 * 16 + r16) * VTS + blk * 8];
          o[n8] = __builtin_amdgcn_mfma_f32_16x16x32_bf16(pa, vb, o[n8], 0, 0, 0);
        }
        __builtin_amdgcn_s_setprio(0);
      }
      __syncthreads();
    }

    #pragma unroll
    for (int j = 0; j < 4; ++j) {
      const float inv = 1.0f / l_j[j];
      const size_t rowoff = (size_t)(qrow0 + g * 4 + j) * OW + h * DVAL;
      #pragma unroll
      for (int n8 = 0; n8 < 8; ++n8)
        att[rowoff + n8 * 16 + r16] = f2b(o[n8][j] * inv);
    }
  }
}

extern "C" void kernel_launch(void* const* d_in, const int* in_sizes, int n_in,
                              void* d_out, int out_size, void* d_ws, size_t ws_size,
                              hipStream_t stream) {
  const float* x      = (const float*)d_in[0];
  const float* wq     = (const float*)d_in[1];
  const float* wkv_a  = (const float*)d_in[2];
  const float* w_norm = (const float*)d_in[3];
  const float* wkv_b  = (const float*)d_in[4];
  const float* wo     = (const float*)d_in[5];
  float* out = (float*)d_out;

  unsigned short* wqT   = (unsigned short*)d_ws;           // 3072 x 2048
  unsigned short* wkvaT = wqT   + (long)QW * ND;           // 640  x 2048
  unsigned short* wkvbT = wkvaT + (long)AWPAD * ND;        // 4096 x 512
  unsigned short* woT   = wkvbT + (long)BW * RANK;         // 2048 x 2048
  unsigned short* xb2   = woT   + (long)ND * OW;           // 2 x 2048 x 2048
  unsigned short* q2    = xb2   + (long)NB * NS * ND;      // 2 x 2048 x 3072
  unsigned short* kva2  = q2    + (long)NB * NS * QW;      // 2 x 2048 x 576
  unsigned short* kvb2  = kva2  + (long)NB * NS * AW;      // 2 x 2048 x 4096
  unsigned short* att2  = xb2;                             // alias (xb2 dead by attn)

  k_transpose<<<dim3(ND / 32, QW / 32),    dim3(256), 0, stream>>>(wq,    wqT,   ND,  QW);
  k_transpose<<<dim3(ND / 32, AWPAD / 32), dim3(256), 0, stream>>>(wkv_a, wkvaT, ND,  AW);
  k_transpose<<<dim3(RANK / 32, BW / 32),  dim3(256), 0, stream>>>(wkv_b, wkvbT, RANK, BW);
  k_transpose<<<dim3(OW / 32, ND / 32),    dim3(256), 0, stream>>>(wo,    woT,   OW,  ND);

  k_cvt<<<dim3((NB * NS * ND) / 1024), dim3(256), 0, stream>>>(x, xb2);
  gemm_bf16<unsigned short><<<dim3(QW / 128, (NB * NS) / 128), dim3(256), 0, stream>>>(
      xb2, wqT, q2, NB * NS, QW, ND, ND);
  gemm_bf16<unsigned short><<<dim3(5, (NB * NS) / 128), dim3(256), 0, stream>>>(
      xb2, wkvaT, kva2, NB * NS, AW, ND, ND);
  k_rms_b<<<dim3(NB * NS), dim3(256), 0, stream>>>(kva2, w_norm);
  k_ropek_b<<<dim3(NB * NS), dim3(64), 0, stream>>>(kva2);
  k_ropeq_b<<<dim3(NB * NS), dim3(512), 0, stream>>>(q2);
  gemm_bf16<unsigned short><<<dim3(BW / 128, (NB * NS) / 128), dim3(256), 0, stream>>>(
      kva2, wkvbT, kvb2, NB * NS, BW, RANK, AW);
  k_attn_mfma<<<dim3(8, NH, NB), dim3(512), 0, stream>>>(q2, kvb2, kva2, att2);
  gemm_bf16<float><<<dim3(ND / 128, (NB * NS) / 128), dim3(256), 0, stream>>>(
      att2, woT, out, NB * NS, ND, OW, OW);
}